// Round 4
// baseline (433.690 us; speedup 1.0000x reference)
//
#include <hip/hip_runtime.h>
#include <stdint.h>

typedef uint32_t u32x4 __attribute__((ext_vector_type(4)));

// Spread the low 8 bits of x to stride-4 positions: bit j -> bit 4*j.
__device__ __forceinline__ uint32_t spread4(uint32_t x) {
    x = (x | (x << 12)) & 0x000F000Fu;
    x = (x | (x << 6))  & 0x03030303u;
    x = (x | (x << 3))  & 0x11111111u;
    return x;
}

// floor() on the fp32 bit pattern, matching the reference bit-level spec:
//  E < 127  -> sign ? bits(-1.0f) : 0
//  E >= 150 -> u unchanged (also covers inf/nan)
//  else     -> truncate low (150-E) mantissa bits; if negative and a cleared
//              bit was set, result = bits(trunc_value - 1.0f)
__device__ __forceinline__ uint32_t floor_bits(uint32_t u) {
    uint32_t E = (u >> 23) & 0xFFu;
    uint32_t s = u >> 31;
    int sh = 150 - (int)E;
    int shc = sh < 1 ? 1 : (sh > 23 ? 23 : sh);   // only used when 127<=E<150
    uint32_t fracmask = (1u << shc) - 1u;
    uint32_t t = u & ~fracmask;
    bool hasfrac = (u & fracmask) != 0u;
    float tm1f = __uint_as_float(t) - 1.0f;       // exact: |t| in [1, 2^23]
    uint32_t r = (s && hasfrac) ? __float_as_uint(tm1f) : t;
    if (E < 127u)  r = s ? 0xBF800000u : 0x00000000u;
    if (E >= 150u) r = u;
    return r;
}

#define TILES 8

// Input: flat (..., 32) fp32 bit-floats (0.0/1.0), MSB first per value.
// Lane loads 4 bit-floats; a wave's 256 bit-floats = 8 values; value
// k = lane>>3. Reconstruct via 4 ballots, each lane re-emits its 4 bits.
// TILES grid-strided vectors per thread; plain (cached) loads/stores so L3
// write-hits on the just-poisoned d_out are exploited.
__global__ __launch_bounds__(256) void spike_floor(const u32x4* __restrict__ in,
                                                   u32x4* __restrict__ out,
                                                   int stride) {           // total threads
    int idx = blockIdx.x * 256 + threadIdx.x;

    u32x4 v[TILES];
#pragma unroll
    for (int t = 0; t < TILES; ++t)
        v[t] = in[idx + t * stride];

    int lane    = threadIdx.x & 63;
    int k8      = (lane >> 3) << 3;      // 8 * (value index within wave)
    int myshift = (lane & 7) << 2;       // this lane's 4-bit window

#pragma unroll
    for (int t = 0; t < TILES; ++t) {
        // bit-floats are exactly 0.0f (0x0) or 1.0f (0x3F800000): int compare ok
        unsigned long long m0 = __ballot(v[t].x != 0u);
        unsigned long long m1 = __ballot(v[t].y != 0u);
        unsigned long long m2 = __ballot(v[t].z != 0u);
        unsigned long long m3 = __ballot(v[t].w != 0u);

        uint32_t b0 = (uint32_t)(m0 >> k8) & 0xFFu;
        uint32_t b1 = (uint32_t)(m1 >> k8) & 0xFFu;
        uint32_t b2 = (uint32_t)(m2 >> k8) & 0xFFu;
        uint32_t b3 = (uint32_t)(m3 >> k8) & 0xFFu;

        // rev8(b_c): bit m -> value bit 4m + (3-c); spread4 then shift (3-c).
        uint32_t u = (spread4(__brev(b0) >> 24) << 3)
                   | (spread4(__brev(b1) >> 24) << 2)
                   | (spread4(__brev(b2) >> 24) << 1)
                   |  spread4(__brev(b3) >> 24);

        uint32_t r  = floor_bits(u);
        uint32_t rs = r << myshift;      // lane's 4 bits now at positions 31..28

        u32x4 o;
        o.x = (rs & 0x80000000u) ? 0x3F800000u : 0u;
        o.y = (rs & 0x40000000u) ? 0x3F800000u : 0u;
        o.z = (rs & 0x20000000u) ? 0x3F800000u : 0u;
        o.w = (rs & 0x10000000u) ? 0x3F800000u : 0u;
        out[idx + t * stride] = o;
    }
}

extern "C" void kernel_launch(void* const* d_in, const int* in_sizes, int n_in,
                              void* d_out, int out_size, void* d_ws, size_t ws_size,
                              hipStream_t stream) {
    const u32x4* in = (const u32x4*)d_in[0];
    u32x4* out = (u32x4*)d_out;
    int n4 = in_sizes[0] / 4;            // 16,777,216 vectors of 4
    int threads_total = n4 / TILES;      // 2,097,152 (exactly divisible)
    int blocks = threads_total / 256;    // 8,192 blocks
    hipLaunchKernelGGL(spike_floor, dim3(blocks), dim3(256), 0, stream,
                       in, out, threads_total);
}

// Round 5
// 410.043 us; speedup vs baseline: 1.0577x; 1.0577x over previous
//
#include <hip/hip_runtime.h>
#include <stdint.h>

typedef uint32_t u32x4 __attribute__((ext_vector_type(4)));

// Spread the low 8 bits of x to stride-4 positions: bit j -> bit 4*j.
__device__ __forceinline__ uint32_t spread4(uint32_t x) {
    x = (x | (x << 12)) & 0x000F000Fu;
    x = (x | (x << 6))  & 0x03030303u;
    x = (x | (x << 3))  & 0x11111111u;
    return x;
}

// floor() on the fp32 bit pattern, matching the reference bit-level spec:
//  E < 127  -> sign ? bits(-1.0f) : 0
//  E >= 150 -> u unchanged (also covers inf/nan)
//  else     -> truncate low (150-E) mantissa bits; if negative and a cleared
//              bit was set, result = bits(trunc_value - 1.0f)
__device__ __forceinline__ uint32_t floor_bits(uint32_t u) {
    uint32_t E = (u >> 23) & 0xFFu;
    uint32_t s = u >> 31;
    int sh = 150 - (int)E;
    int shc = sh < 1 ? 1 : (sh > 23 ? 23 : sh);   // only used when 127<=E<150
    uint32_t fracmask = (1u << shc) - 1u;
    uint32_t t = u & ~fracmask;
    bool hasfrac = (u & fracmask) != 0u;
    float tm1f = __uint_as_float(t) - 1.0f;       // exact: |t| in [1, 2^23]
    uint32_t r = (s && hasfrac) ? __float_as_uint(tm1f) : t;
    if (E < 127u)  r = s ? 0xBF800000u : 0x00000000u;
    if (E >= 150u) r = u;
    return r;
}

// Input: flat (..., 32) fp32 bit-floats (0.0/1.0), MSB first per value.
// One lane loads one uint4 (4 bit-floats); a wave's 256 bit-floats = 8
// values; value k = lane>>3 spans lanes [8k,8k+8). Reconstruct the 32-bit
// word via 4 ballots; each lane computes floor and re-emits its own 4 bits.
// TILES=1 (single vector per thread) measured fastest: R1=413.6 µs vs
// TILES=4 nt=419.0, TILES=8 cached=433.7 — MLP is not the limiter
// (32 KB/CU in flight >> 9 KB needed), extra tiles only add index overhead.
__global__ __launch_bounds__(256) void spike_floor(const u32x4* __restrict__ in,
                                                   u32x4* __restrict__ out,
                                                   int n4) {
    int idx = blockIdx.x * 256 + threadIdx.x;
    if (idx >= n4) return;
    u32x4 v = in[idx];

    // bit-floats are exactly 0.0f (0x0) or 1.0f (0x3F800000): int compare ok
    unsigned long long m0 = __ballot(v.x != 0u);
    unsigned long long m1 = __ballot(v.y != 0u);
    unsigned long long m2 = __ballot(v.z != 0u);
    unsigned long long m3 = __ballot(v.w != 0u);

    int lane = threadIdx.x & 63;
    int k8   = (lane >> 3) << 3;         // 8 * (value index within wave)

    uint32_t b0 = (uint32_t)(m0 >> k8) & 0xFFu;
    uint32_t b1 = (uint32_t)(m1 >> k8) & 0xFFu;
    uint32_t b2 = (uint32_t)(m2 >> k8) & 0xFFu;
    uint32_t b3 = (uint32_t)(m3 >> k8) & 0xFFu;

    // rev8(b_c): bit m -> value bit 4m + (3-c); spread4 then shift (3-c).
    uint32_t u = (spread4(__brev(b0) >> 24) << 3)
               | (spread4(__brev(b1) >> 24) << 2)
               | (spread4(__brev(b2) >> 24) << 1)
               |  spread4(__brev(b3) >> 24);

    uint32_t r  = floor_bits(u);
    uint32_t rs = r << ((lane & 7) << 2);   // lane's 4 bits at positions 31..28

    u32x4 o;
    o.x = (rs & 0x80000000u) ? 0x3F800000u : 0u;
    o.y = (rs & 0x40000000u) ? 0x3F800000u : 0u;
    o.z = (rs & 0x20000000u) ? 0x3F800000u : 0u;
    o.w = (rs & 0x10000000u) ? 0x3F800000u : 0u;
    out[idx] = o;
}

extern "C" void kernel_launch(void* const* d_in, const int* in_sizes, int n_in,
                              void* d_out, int out_size, void* d_ws, size_t ws_size,
                              hipStream_t stream) {
    const u32x4* in = (const u32x4*)d_in[0];
    u32x4* out = (u32x4*)d_out;
    int n4 = in_sizes[0] / 4;            // 16,777,216 vectors (divisible by 256)
    int blocks = (n4 + 255) / 256;       // 65,536 blocks
    hipLaunchKernelGGL(spike_floor, dim3(blocks), dim3(256), 0, stream,
                       in, out, n4);
}